// Round 1
// baseline (27157.950 us; speedup 1.0000x reference)
//
#include <hip/hip_runtime.h>
#include <hip/hip_bf16.h>

#define T_STEPS 2048
#define BATCH   64
#define HID     512
#define GATES   2048   // 4*HID

typedef __attribute__((ext_vector_type(8))) short short8;
typedef __attribute__((ext_vector_type(4))) float f32x4;

__device__ inline unsigned short f2bf(float f) {
  union { float f; unsigned u; } v; v.f = f;
  unsigned r = v.u + 0x7fffu + ((v.u >> 16) & 1u);
  return (unsigned short)(r >> 16);
}
__device__ inline float bf2f(unsigned short s) {
  union { unsigned u; float f; } v; v.u = ((unsigned)s) << 16;
  return v.f;
}
__device__ inline float sigmoidf_(float x) { return 1.f / (1.f + __expf(-x)); }
__device__ inline float tanhf_(float x)    { return 2.f / (1.f + __expf(-2.f * x)) - 1.f; }

// ---------------- Projection GEMM: xg[t][b][g] = A[m] @ W^T + b1 + b2 (bf16 out) ----
// A: M=131072 rows, K=512 contiguous. W: [2048][512] fp32. Tiles 128x128, BK=64.
template<int ABF16, int TROWS>
__global__ __launch_bounds__(256) void proj_kernel(
    const void* __restrict__ Aptr, const float* __restrict__ W,
    const float* __restrict__ bias1, const float* __restrict__ bias2,
    unsigned short* __restrict__ out)
{
  __shared__ short As[128][72];
  __shared__ short Bs[128][72];
  const int tid  = threadIdx.x;
  const int lane = tid & 63;
  const int wv   = tid >> 6;
  const int wm   = wv >> 1, wn = wv & 1;
  const int bid  = blockIdx.x;
  const int nt   = bid & 15;
  const long mbase = (long)(bid >> 4) * 128;
  const int  nbase = nt * 128;

  f32x4 acc[4][4] = {};

  const int r  = tid >> 1;        // 0..127
  const int kh = (tid & 1) * 32;  // k offset within BK

  for (int kt = 0; kt < 8; ++kt) {
    if (ABF16) {
      const unsigned short* src = (const unsigned short*)Aptr + (mbase + r) * 512 + kt * 64 + kh;
      *(short8*)&As[r][kh]      = *(const short8*)(src);
      *(short8*)&As[r][kh + 8]  = *(const short8*)(src + 8);
      *(short8*)&As[r][kh + 16] = *(const short8*)(src + 16);
      *(short8*)&As[r][kh + 24] = *(const short8*)(src + 24);
    } else {
      const float* src = (const float*)Aptr + (mbase + r) * 512 + kt * 64 + kh;
#pragma unroll
      for (int j = 0; j < 4; ++j) {
        float4 v0 = *(const float4*)(src + j * 8);
        float4 v1 = *(const float4*)(src + j * 8 + 4);
        short8 p;
        p[0] = (short)f2bf(v0.x); p[1] = (short)f2bf(v0.y);
        p[2] = (short)f2bf(v0.z); p[3] = (short)f2bf(v0.w);
        p[4] = (short)f2bf(v1.x); p[5] = (short)f2bf(v1.y);
        p[6] = (short)f2bf(v1.z); p[7] = (short)f2bf(v1.w);
        *(short8*)&As[r][kh + j * 8] = p;
      }
    }
    {
      const float* src = W + (size_t)(nbase + r) * 512 + kt * 64 + kh;
#pragma unroll
      for (int j = 0; j < 4; ++j) {
        float4 v0 = *(const float4*)(src + j * 8);
        float4 v1 = *(const float4*)(src + j * 8 + 4);
        short8 p;
        p[0] = (short)f2bf(v0.x); p[1] = (short)f2bf(v0.y);
        p[2] = (short)f2bf(v0.z); p[3] = (short)f2bf(v0.w);
        p[4] = (short)f2bf(v1.x); p[5] = (short)f2bf(v1.y);
        p[6] = (short)f2bf(v1.z); p[7] = (short)f2bf(v1.w);
        *(short8*)&Bs[r][kh + j * 8] = p;
      }
    }
    __syncthreads();
#pragma unroll
    for (int kk = 0; kk < 2; ++kk) {
      const int kc = kk * 32 + ((lane >> 4) & 3) * 8;
      short8 af[4], bfr[4];
#pragma unroll
      for (int i = 0; i < 4; ++i)
        af[i] = *(const short8*)&As[wm * 64 + i * 16 + (lane & 15)][kc];
#pragma unroll
      for (int i = 0; i < 4; ++i)
        bfr[i] = *(const short8*)&Bs[wn * 64 + i * 16 + (lane & 15)][kc];
#pragma unroll
      for (int i = 0; i < 4; ++i)
#pragma unroll
        for (int j = 0; j < 4; ++j)
          acc[i][j] = __builtin_amdgcn_mfma_f32_16x16x32_bf16(af[i], bfr[j], acc[i][j], 0, 0, 0);
    }
    __syncthreads();
  }
  // epilogue: bias + bf16 store into xg[t*64+b][g]
#pragma unroll
  for (int j = 0; j < 4; ++j) {
    const int n = nbase + wn * 64 + j * 16 + (lane & 15);
    const float bsum = bias1[n] + bias2[n];
#pragma unroll
    for (int i = 0; i < 4; ++i) {
      f32x4 v = acc[i][j];
#pragma unroll
      for (int e = 0; e < 4; ++e) {
        long m = mbase + wm * 64 + i * 16 + ((lane >> 4) & 3) * 4 + e;
        long orow = TROWS ? ((m & 2047) * 64 + (m >> 11)) : m;
        out[orow * 2048 + n] = f2bf(v[e] + bsum);
      }
    }
  }
}

// ---------------- Persistent scan: 64 WGs = 4 batch-groups x 16 unit-slices --------
// WG: 256 thr. LDS: W slice [128][512] bf16 swizzled + gate buf + c state.
template<int LAYER>
__global__ __launch_bounds__(256) void scan_kernel(
    const unsigned short* __restrict__ xg,     // [T][64][2048] bf16
    const float* __restrict__ Whh,             // [2048][512] fp32
    unsigned short* __restrict__ hhist,        // [T+1][64][512] bf16 (this layer)
    float* __restrict__ dout,
    int* __restrict__ arrive)                  // [4][T+1]
{
  extern __shared__ char smem[];
  float* gbuf = (float*)(smem + 131072);               // [16][132]
  float* cbuf = (float*)(smem + 131072 + 16 * 132 * 4); // [16][32]

  const int tid  = threadIdx.x;
  const int lane = tid & 63;
  const int wv   = tid >> 6;
  const int s    = blockIdx.x & 15;   // unit slice
  const int grp  = blockIdx.x >> 4;   // batch group
  const int u_base = s * 32;
  const int b_base = grp * 16;
  int* arr = arrive + grp * (T_STEPS + 1);

  // ---- load W slice into LDS (bf16, XOR-swizzled rows) ----
  {
    const int r    = tid >> 1;          // 0..127 slice row
    const int kh   = (tid & 1) * 256;   // k half
    const int type = r >> 5, uu = r & 31;
    const float* src = Whh + (size_t)(type * 512 + u_base + uu) * 512 + kh;
    const int rowbyte = r * 1024;
    const int sw = (r & 7) << 4;
#pragma unroll 4
    for (int j = 0; j < 32; ++j) {
      float4 v0 = *(const float4*)(src + j * 8);
      float4 v1 = *(const float4*)(src + j * 8 + 4);
      short8 p;
      p[0] = (short)f2bf(v0.x); p[1] = (short)f2bf(v0.y);
      p[2] = (short)f2bf(v0.z); p[3] = (short)f2bf(v0.w);
      p[4] = (short)f2bf(v1.x); p[5] = (short)f2bf(v1.y);
      p[6] = (short)f2bf(v1.z); p[7] = (short)f2bf(v1.w);
      int byte = rowbyte + (kh + j * 8) * 2;
      *(short8*)(smem + (byte ^ sw)) = p;
    }
  }
  cbuf[tid] = 0.f; cbuf[tid + 256] = 0.f;
  __syncthreads();

  const int bb = tid >> 4;          // cell-phase batch row
  const int u0 = (tid & 15) * 2;    // cell-phase unit pair

  for (int t = 0; t < T_STEPS; ++t) {
    // prefetch xg slice for this step (4 dwords = 8 bf16)
    unsigned xgp[4];
    {
      const size_t base = ((size_t)t * 64 + b_base + bb) * 2048 + u_base + u0;
      xgp[0] = *(const unsigned*)(xg + base);
      xgp[1] = *(const unsigned*)(xg + base + 512);
      xgp[2] = *(const unsigned*)(xg + base + 1024);
      xgp[3] = *(const unsigned*)(xg + base + 1536);
    }

    f32x4 acc0 = {0.f, 0.f, 0.f, 0.f}, acc1 = {0.f, 0.f, 0.f, 0.f};
    if (t > 0) {
      if (tid == 0) {
        while (__hip_atomic_load(arr + t, __ATOMIC_RELAXED, __HIP_MEMORY_SCOPE_AGENT) < 16)
          __builtin_amdgcn_s_sleep(2);
      }
      __syncthreads();
      __builtin_amdgcn_fence(__ATOMIC_ACQUIRE, "agent");

      // gates[b][r] = sum_k h[t][b_base+b][k] * Ws[r][k]
      const unsigned short* hrow = hhist + (size_t)t * (64 * 512)
          + (size_t)(b_base + (lane & 15)) * 512 + ((lane >> 4) & 3) * 8;
      const int rowA = wv * 32 + (lane & 15);
      const int rowB = rowA + 16;
      const int kb   = ((lane >> 4) & 3) * 16;
      const int swA  = (rowA & 7) << 4;
      const int swB  = (rowB & 7) << 4;
#pragma unroll 4
      for (int kt = 0; kt < 16; ++kt) {
        short8 af = *(const short8*)(hrow + kt * 32);
        short8 b0 = *(const short8*)(smem + ((rowA * 1024 + kt * 64 + kb) ^ swA));
        short8 b1 = *(const short8*)(smem + ((rowB * 1024 + kt * 64 + kb) ^ swB));
        acc0 = __builtin_amdgcn_mfma_f32_16x16x32_bf16(af, b0, acc0, 0, 0, 0);
        acc1 = __builtin_amdgcn_mfma_f32_16x16x32_bf16(af, b1, acc1, 0, 0, 0);
      }
    }
    // write gates to LDS
    {
      const int m0 = ((lane >> 4) & 3) * 4;
      const int cA = wv * 32 + (lane & 15);
#pragma unroll
      for (int e = 0; e < 4; ++e) {
        gbuf[(m0 + e) * 132 + cA]      = acc0[e];
        gbuf[(m0 + e) * 132 + cA + 16] = acc1[e];
      }
    }
    __syncthreads();

    // cell update: each thread owns (bb, u0) and (bb, u0+1)
    float hv[2], cv[2];
#pragma unroll
    for (int q = 0; q < 2; ++q) {
      const int u = u0 + q;
      float ig = gbuf[bb * 132 + u]        + bf2f((unsigned short)(xgp[0] >> (16 * q)));
      float fg = gbuf[bb * 132 + 32 + u]   + bf2f((unsigned short)(xgp[1] >> (16 * q)));
      float gg = gbuf[bb * 132 + 64 + u]   + bf2f((unsigned short)(xgp[2] >> (16 * q)));
      float og = gbuf[bb * 132 + 96 + u]   + bf2f((unsigned short)(xgp[3] >> (16 * q)));
      float iv = sigmoidf_(ig), fv = sigmoidf_(fg);
      float gv = tanhf_(gg),    ov = sigmoidf_(og);
      float c = fv * cbuf[bb * 32 + u] + iv * gv;
      cbuf[bb * 32 + u] = c;
      float h = ov * tanhf_(c);
      hv[q] = h; cv[q] = c;
    }
    {
      unsigned hp = (unsigned)f2bf(hv[0]) | ((unsigned)f2bf(hv[1]) << 16);
      *(unsigned*)(hhist + (size_t)(t + 1) * (64 * 512) + (size_t)(b_base + bb) * 512 + u_base + u0) = hp;
      if (LAYER == 1) {
        float2 ho; ho.x = hv[0]; ho.y = hv[1];
        *(float2*)(dout + (size_t)(b_base + bb) * ((size_t)T_STEPS * 512) + (size_t)t * 512 + u_base + u0) = ho;
      }
      if (t == T_STEPS - 1) {
        const size_t OUT0 = (size_t)64 * 2048 * 512;
        size_t o  = OUT0 + (size_t)LAYER * 32768 + (size_t)(b_base + bb) * 512 + u_base + u0;
        dout[o]     = hv[0];
        dout[o + 1] = hv[1];
        size_t oc = o + 65536;
        dout[oc]     = cv[0];
        dout[oc + 1] = cv[1];
      }
    }
    __syncthreads();   // drains vmem: all h stores done before publish
    if (tid == 0)
      __hip_atomic_fetch_add(arr + t + 1, 1, __ATOMIC_RELEASE, __HIP_MEMORY_SCOPE_AGENT);
  }
}

extern "C" void kernel_launch(void* const* d_in, const int* in_sizes, int n_in,
                              void* d_out, int out_size, void* d_ws, size_t ws_size,
                              hipStream_t stream) {
  const float* x    = (const float*)d_in[0];
  const float* Wih0 = (const float*)d_in[1];
  const float* Whh0 = (const float*)d_in[2];
  const float* bih0 = (const float*)d_in[3];
  const float* bhh0 = (const float*)d_in[4];
  const float* Wih1 = (const float*)d_in[5];
  const float* Whh1 = (const float*)d_in[6];
  const float* bih1 = (const float*)d_in[7];
  const float* bhh1 = (const float*)d_in[8];
  float* out = (float*)d_out;

  const size_t XG_BYTES = (size_t)T_STEPS * 64 * 2048 * 2;       // 536,870,912
  const size_t H_BYTES  = (size_t)(T_STEPS + 1) * 64 * 512 * 2;  // 134,283,264
  const size_t AR_BYTES = (size_t)2 * 4 * (T_STEPS + 1) * 4;
  if (ws_size < XG_BYTES + 2 * H_BYTES + AR_BYTES) return;  // ws too small: clean fail

  char* ws = (char*)d_ws;
  unsigned short* xg = (unsigned short*)ws;
  unsigned short* h0 = (unsigned short*)(ws + XG_BYTES);
  unsigned short* h1 = (unsigned short*)(ws + XG_BYTES + H_BYTES);
  int* arrive        = (int*)(ws + XG_BYTES + 2 * H_BYTES);

  hipMemsetAsync(arrive, 0, AR_BYTES, stream);

  const int smem_scan = 131072 + 16 * 132 * 4 + 2048;  // 141,568 B
  hipFuncSetAttribute((const void*)scan_kernel<0>, hipFuncAttributeMaxDynamicSharedMemorySize, smem_scan);
  hipFuncSetAttribute((const void*)scan_kernel<1>, hipFuncAttributeMaxDynamicSharedMemorySize, smem_scan);

  proj_kernel<0, 1><<<dim3(16384), dim3(256), 0, stream>>>(x, Wih0, bih0, bhh0, xg);
  scan_kernel<0><<<dim3(64), dim3(256), smem_scan, stream>>>(xg, Whh0, h0, out, arrive);
  proj_kernel<1, 0><<<dim3(16384), dim3(256), 0, stream>>>(h0 + 32768, Wih1, bih1, bhh1, xg);
  scan_kernel<1><<<dim3(64), dim3(256), smem_scan, stream>>>(xg, Whh1, h1, out, arrive + 4 * (T_STEPS + 1));
}

// Round 2
// 25842.383 us; speedup vs baseline: 1.0509x; 1.0509x over previous
//
#include <hip/hip_runtime.h>
#include <hip/hip_bf16.h>

#define T_STEPS 2048
#define BATCH   64
#define HID     512
#define GATES   2048   // 4*HID

typedef __attribute__((ext_vector_type(8))) short short8;
typedef __attribute__((ext_vector_type(4))) float f32x4;

__device__ inline unsigned short f2bf(float f) {
  union { float f; unsigned u; } v; v.f = f;
  unsigned r = v.u + 0x7fffu + ((v.u >> 16) & 1u);
  return (unsigned short)(r >> 16);
}
__device__ inline float bf2f(unsigned short s) {
  union { unsigned u; float f; } v; v.u = ((unsigned)s) << 16;
  return v.f;
}
__device__ inline float sigmoidf_(float x) { return 1.f / (1.f + __expf(-x)); }
__device__ inline float tanhf_(float x)    { return 2.f / (1.f + __expf(-2.f * x)) - 1.f; }

// ---------------- Projection GEMM: xg[t][b][g] = A[m] @ W^T + b1 + b2 (bf16 out) ----
template<int ABF16, int TROWS>
__global__ __launch_bounds__(256) void proj_kernel(
    const void* __restrict__ Aptr, const float* __restrict__ W,
    const float* __restrict__ bias1, const float* __restrict__ bias2,
    unsigned short* __restrict__ out)
{
  __shared__ short As[128][72];
  __shared__ short Bs[128][72];
  const int tid  = threadIdx.x;
  const int lane = tid & 63;
  const int wv   = tid >> 6;
  const int wm   = wv >> 1, wn = wv & 1;
  const int bid  = blockIdx.x;
  const int nt   = bid & 15;
  const long mbase = (long)(bid >> 4) * 128;
  const int  nbase = nt * 128;

  f32x4 acc[4][4] = {};

  const int r  = tid >> 1;        // 0..127
  const int kh = (tid & 1) * 32;  // k offset within BK

  for (int kt = 0; kt < 8; ++kt) {
    if (ABF16) {
      const unsigned short* src = (const unsigned short*)Aptr + (mbase + r) * 512 + kt * 64 + kh;
      *(short8*)&As[r][kh]      = *(const short8*)(src);
      *(short8*)&As[r][kh + 8]  = *(const short8*)(src + 8);
      *(short8*)&As[r][kh + 16] = *(const short8*)(src + 16);
      *(short8*)&As[r][kh + 24] = *(const short8*)(src + 24);
    } else {
      const float* src = (const float*)Aptr + (mbase + r) * 512 + kt * 64 + kh;
#pragma unroll
      for (int j = 0; j < 4; ++j) {
        float4 v0 = *(const float4*)(src + j * 8);
        float4 v1 = *(const float4*)(src + j * 8 + 4);
        short8 p;
        p[0] = (short)f2bf(v0.x); p[1] = (short)f2bf(v0.y);
        p[2] = (short)f2bf(v0.z); p[3] = (short)f2bf(v0.w);
        p[4] = (short)f2bf(v1.x); p[5] = (short)f2bf(v1.y);
        p[6] = (short)f2bf(v1.z); p[7] = (short)f2bf(v1.w);
        *(short8*)&As[r][kh + j * 8] = p;
      }
    }
    {
      const float* src = W + (size_t)(nbase + r) * 512 + kt * 64 + kh;
#pragma unroll
      for (int j = 0; j < 4; ++j) {
        float4 v0 = *(const float4*)(src + j * 8);
        float4 v1 = *(const float4*)(src + j * 8 + 4);
        short8 p;
        p[0] = (short)f2bf(v0.x); p[1] = (short)f2bf(v0.y);
        p[2] = (short)f2bf(v0.z); p[3] = (short)f2bf(v0.w);
        p[4] = (short)f2bf(v1.x); p[5] = (short)f2bf(v1.y);
        p[6] = (short)f2bf(v1.z); p[7] = (short)f2bf(v1.w);
        *(short8*)&Bs[r][kh + j * 8] = p;
      }
    }
    __syncthreads();
#pragma unroll
    for (int kk = 0; kk < 2; ++kk) {
      const int kc = kk * 32 + ((lane >> 4) & 3) * 8;
      short8 af[4], bfr[4];
#pragma unroll
      for (int i = 0; i < 4; ++i)
        af[i] = *(const short8*)&As[wm * 64 + i * 16 + (lane & 15)][kc];
#pragma unroll
      for (int i = 0; i < 4; ++i)
        bfr[i] = *(const short8*)&Bs[wn * 64 + i * 16 + (lane & 15)][kc];
#pragma unroll
      for (int i = 0; i < 4; ++i)
#pragma unroll
        for (int j = 0; j < 4; ++j)
          acc[i][j] = __builtin_amdgcn_mfma_f32_16x16x32_bf16(af[i], bfr[j], acc[i][j], 0, 0, 0);
    }
    __syncthreads();
  }
#pragma unroll
  for (int j = 0; j < 4; ++j) {
    const int n = nbase + wn * 64 + j * 16 + (lane & 15);
    const float bsum = bias1[n] + bias2[n];
#pragma unroll
    for (int i = 0; i < 4; ++i) {
      f32x4 v = acc[i][j];
#pragma unroll
      for (int e = 0; e < 4; ++e) {
        long m = mbase + wm * 64 + i * 16 + ((lane >> 4) & 3) * 4 + e;
        long orow = TROWS ? ((m & 2047) * 64 + (m >> 11)) : m;
        out[orow * 2048 + n] = f2bf(v[e] + bsum);
      }
    }
  }
}

// ---------------- Persistent scan: 64 WGs = 4 batch-groups x 16 unit-slices --------
// Fenceless cross-WG sync: h data moves via sc0+sc1 (L3-coherent) ops; per-slice
// step flags via relaxed agent fetch_add/load. No release/acquire fences per step.
template<int LAYER>
__global__ __launch_bounds__(256) void scan_kernel(
    const unsigned short* __restrict__ xg,     // [T][64][2048] bf16
    const float* __restrict__ Whh,             // [2048][512] fp32
    unsigned short* __restrict__ hhist,        // [T+1][64][512] bf16 (this layer)
    float* __restrict__ dout,
    int* __restrict__ flags)                   // [4][16] step counters (this layer)
{
  extern __shared__ char smem[];
  float* gbuf = (float*)(smem + 131072);               // [16][132]
  float* cbuf = (float*)(smem + 131072 + 16 * 132 * 4); // [16][32]

  const int tid  = threadIdx.x;
  const int lane = tid & 63;
  const int wv   = tid >> 6;
  const int s    = blockIdx.x & 15;   // unit slice
  const int grp  = blockIdx.x >> 4;   // batch group
  const int u_base = s * 32;
  const int b_base = grp * 16;
  int* gflags = flags + grp * 16;

  // ---- load W slice into LDS (bf16, XOR-swizzled rows) ----
  {
    const int r    = tid >> 1;          // 0..127 slice row
    const int kh   = (tid & 1) * 256;   // k half
    const int type = r >> 5, uu = r & 31;
    const float* src = Whh + (size_t)(type * 512 + u_base + uu) * 512 + kh;
    const int rowbyte = r * 1024;
    const int sw = (r & 7) << 4;
#pragma unroll 4
    for (int j = 0; j < 32; ++j) {
      float4 v0 = *(const float4*)(src + j * 8);
      float4 v1 = *(const float4*)(src + j * 8 + 4);
      short8 p;
      p[0] = (short)f2bf(v0.x); p[1] = (short)f2bf(v0.y);
      p[2] = (short)f2bf(v0.z); p[3] = (short)f2bf(v0.w);
      p[4] = (short)f2bf(v1.x); p[5] = (short)f2bf(v1.y);
      p[6] = (short)f2bf(v1.z); p[7] = (short)f2bf(v1.w);
      int byte = rowbyte + (kh + j * 8) * 2;
      *(short8*)(smem + (byte ^ sw)) = p;
    }
  }
  cbuf[tid] = 0.f; cbuf[tid + 256] = 0.f;
  __syncthreads();

  const int bb = tid >> 4;          // cell-phase batch row
  const int u0 = (tid & 15) * 2;    // cell-phase unit pair

  const int rowA = wv * 32 + (lane & 15);
  const int rowB = rowA + 16;
  const int kb   = ((lane >> 4) & 3) * 16;
  const int swA  = (rowA & 7) << 4;
  const int swB  = (rowB & 7) << 4;

  for (int t = 0; t < T_STEPS; ++t) {
    f32x4 acc0 = {0.f, 0.f, 0.f, 0.f}, acc1 = {0.f, 0.f, 0.f, 0.f};
    unsigned xgp[4];

    if (t > 0) {
      // ---- wait for all 16 producers of h[t] (relaxed agent loads, no fence) ----
      {
        int f;
        do {
          f = __hip_atomic_load(&gflags[lane & 15], __ATOMIC_RELAXED, __HIP_MEMORY_SCOPE_AGENT);
        } while (!__all(f >= t));
      }
      // ---- h[t] fragment loads, L3-coherent (sc0 sc1), one asm block ----
      const unsigned short* hrow = hhist + (size_t)t * (64 * 512)
          + (size_t)(b_base + (lane & 15)) * 512 + ((lane >> 4) & 3) * 8;
      short8 hh[16];
      asm volatile(
        "global_load_dwordx4 %0, %16, off sc0 sc1\n\t"
        "global_load_dwordx4 %1, %16, off offset:64 sc0 sc1\n\t"
        "global_load_dwordx4 %2, %16, off offset:128 sc0 sc1\n\t"
        "global_load_dwordx4 %3, %16, off offset:192 sc0 sc1\n\t"
        "global_load_dwordx4 %4, %16, off offset:256 sc0 sc1\n\t"
        "global_load_dwordx4 %5, %16, off offset:320 sc0 sc1\n\t"
        "global_load_dwordx4 %6, %16, off offset:384 sc0 sc1\n\t"
        "global_load_dwordx4 %7, %16, off offset:448 sc0 sc1\n\t"
        "global_load_dwordx4 %8, %16, off offset:512 sc0 sc1\n\t"
        "global_load_dwordx4 %9, %16, off offset:576 sc0 sc1\n\t"
        "global_load_dwordx4 %10, %16, off offset:640 sc0 sc1\n\t"
        "global_load_dwordx4 %11, %16, off offset:704 sc0 sc1\n\t"
        "global_load_dwordx4 %12, %16, off offset:768 sc0 sc1\n\t"
        "global_load_dwordx4 %13, %16, off offset:832 sc0 sc1\n\t"
        "global_load_dwordx4 %14, %16, off offset:896 sc0 sc1\n\t"
        "global_load_dwordx4 %15, %16, off offset:960 sc0 sc1\n\t"
        "s_waitcnt vmcnt(0)"
        : "=&v"(hh[0]), "=&v"(hh[1]), "=&v"(hh[2]), "=&v"(hh[3]),
          "=&v"(hh[4]), "=&v"(hh[5]), "=&v"(hh[6]), "=&v"(hh[7]),
          "=&v"(hh[8]), "=&v"(hh[9]), "=&v"(hh[10]), "=&v"(hh[11]),
          "=&v"(hh[12]), "=&v"(hh[13]), "=&v"(hh[14]), "=&v"(hh[15])
        : "v"(hrow)
        : "memory");
      __builtin_amdgcn_sched_barrier(0);

      // xg prefetch AFTER h loads: overlaps the MFMA loop, consumed in cell phase
      {
        const size_t base = ((size_t)t * 64 + b_base + bb) * 2048 + u_base + u0;
        xgp[0] = *(const unsigned*)(xg + base);
        xgp[1] = *(const unsigned*)(xg + base + 512);
        xgp[2] = *(const unsigned*)(xg + base + 1024);
        xgp[3] = *(const unsigned*)(xg + base + 1536);
      }

#pragma unroll
      for (int kt = 0; kt < 16; ++kt) {
        short8 b0 = *(const short8*)(smem + ((rowA * 1024 + kt * 64 + kb) ^ swA));
        short8 b1 = *(const short8*)(smem + ((rowB * 1024 + kt * 64 + kb) ^ swB));
        acc0 = __builtin_amdgcn_mfma_f32_16x16x32_bf16(hh[kt], b0, acc0, 0, 0, 0);
        acc1 = __builtin_amdgcn_mfma_f32_16x16x32_bf16(hh[kt], b1, acc1, 0, 0, 0);
      }
    } else {
      const size_t base = ((size_t)t * 64 + b_base + bb) * 2048 + u_base + u0;
      xgp[0] = *(const unsigned*)(xg + base);
      xgp[1] = *(const unsigned*)(xg + base + 512);
      xgp[2] = *(const unsigned*)(xg + base + 1024);
      xgp[3] = *(const unsigned*)(xg + base + 1536);
    }

    // write gates to LDS
    {
      const int m0 = ((lane >> 4) & 3) * 4;
      const int cA = wv * 32 + (lane & 15);
#pragma unroll
      for (int e = 0; e < 4; ++e) {
        gbuf[(m0 + e) * 132 + cA]      = acc0[e];
        gbuf[(m0 + e) * 132 + cA + 16] = acc1[e];
      }
    }
    __syncthreads();

    // cell update: each thread owns (bb, u0) and (bb, u0+1)
    float hv[2], cv[2];
#pragma unroll
    for (int q = 0; q < 2; ++q) {
      const int u = u0 + q;
      float ig = gbuf[bb * 132 + u]        + bf2f((unsigned short)(xgp[0] >> (16 * q)));
      float fg = gbuf[bb * 132 + 32 + u]   + bf2f((unsigned short)(xgp[1] >> (16 * q)));
      float gg = gbuf[bb * 132 + 64 + u]   + bf2f((unsigned short)(xgp[2] >> (16 * q)));
      float og = gbuf[bb * 132 + 96 + u]   + bf2f((unsigned short)(xgp[3] >> (16 * q)));
      float iv = sigmoidf_(ig), fv = sigmoidf_(fg);
      float gv = tanhf_(gg),    ov = sigmoidf_(og);
      float c = fv * cbuf[bb * 32 + u] + iv * gv;
      cbuf[bb * 32 + u] = c;
      float h = ov * tanhf_(c);
      hv[q] = h; cv[q] = c;
    }
    {
      unsigned hp = (unsigned)f2bf(hv[0]) | ((unsigned)f2bf(hv[1]) << 16);
      // L3-coherent h publish (sc0 sc1): visible to all XCDs once vmcnt drains
      __hip_atomic_store(
          (unsigned*)(hhist + (size_t)(t + 1) * (64 * 512) + (size_t)(b_base + bb) * 512 + u_base + u0),
          hp, __ATOMIC_RELAXED, __HIP_MEMORY_SCOPE_AGENT);
      if (LAYER == 1) {
        float2 ho; ho.x = hv[0]; ho.y = hv[1];
        *(float2*)(dout + (size_t)(b_base + bb) * ((size_t)T_STEPS * 512) + (size_t)t * 512 + u_base + u0) = ho;
      }
      if (t == T_STEPS - 1) {
        const size_t OUT0 = (size_t)64 * 2048 * 512;
        size_t o  = OUT0 + (size_t)LAYER * 32768 + (size_t)(b_base + bb) * 512 + u_base + u0;
        dout[o]     = hv[0];
        dout[o + 1] = hv[1];
        size_t oc = o + 65536;
        dout[oc]     = cv[0];
        dout[oc + 1] = cv[1];
      }
    }
    __syncthreads();   // compiler emits s_waitcnt vmcnt(0) before s_barrier: h stores acked
    if (tid == 0)
      __hip_atomic_fetch_add(&gflags[s], 1, __ATOMIC_RELAXED, __HIP_MEMORY_SCOPE_AGENT);
  }
}

extern "C" void kernel_launch(void* const* d_in, const int* in_sizes, int n_in,
                              void* d_out, int out_size, void* d_ws, size_t ws_size,
                              hipStream_t stream) {
  const float* x    = (const float*)d_in[0];
  const float* Wih0 = (const float*)d_in[1];
  const float* Whh0 = (const float*)d_in[2];
  const float* bih0 = (const float*)d_in[3];
  const float* bhh0 = (const float*)d_in[4];
  const float* Wih1 = (const float*)d_in[5];
  const float* Whh1 = (const float*)d_in[6];
  const float* bih1 = (const float*)d_in[7];
  const float* bhh1 = (const float*)d_in[8];
  float* out = (float*)d_out;

  const size_t XG_BYTES   = (size_t)T_STEPS * 64 * 2048 * 2;       // 536,870,912
  const size_t H_BYTES    = (size_t)(T_STEPS + 1) * 64 * 512 * 2;  // 134,283,264
  const size_t FLAG_BYTES = (size_t)2 * 4 * 16 * 4;                // 512
  if (ws_size < XG_BYTES + 2 * H_BYTES + FLAG_BYTES) return;

  char* ws = (char*)d_ws;
  unsigned short* xg = (unsigned short*)ws;
  unsigned short* h0 = (unsigned short*)(ws + XG_BYTES);
  unsigned short* h1 = (unsigned short*)(ws + XG_BYTES + H_BYTES);
  int* flags         = (int*)(ws + XG_BYTES + 2 * H_BYTES);

  hipMemsetAsync(flags, 0, FLAG_BYTES, stream);

  const int smem_scan = 131072 + 16 * 132 * 4 + 2048;  // 141,568 B
  hipFuncSetAttribute((const void*)scan_kernel<0>, hipFuncAttributeMaxDynamicSharedMemorySize, smem_scan);
  hipFuncSetAttribute((const void*)scan_kernel<1>, hipFuncAttributeMaxDynamicSharedMemorySize, smem_scan);

  proj_kernel<0, 1><<<dim3(16384), dim3(256), 0, stream>>>(x, Wih0, bih0, bhh0, xg);
  scan_kernel<0><<<dim3(64), dim3(256), smem_scan, stream>>>(xg, Whh0, h0, out, flags);
  proj_kernel<1, 0><<<dim3(16384), dim3(256), 0, stream>>>(h0 + 32768, Wih1, bih1, bhh1, xg);
  scan_kernel<1><<<dim3(64), dim3(256), smem_scan, stream>>>(xg, Whh1, h1, out, flags + 64);
}

// Round 3
// 17228.328 us; speedup vs baseline: 1.5764x; 1.5000x over previous
//
#include <hip/hip_runtime.h>
#include <hip/hip_bf16.h>

#define T_STEPS 2048
#define BATCH   64
#define HID     512
#define GATES   2048   // 4*HID

typedef __attribute__((ext_vector_type(8))) short short8;
typedef __attribute__((ext_vector_type(4))) float f32x4;

__device__ inline unsigned short f2bf(float f) {
  union { float f; unsigned u; } v; v.f = f;
  unsigned r = v.u + 0x7fffu + ((v.u >> 16) & 1u);
  return (unsigned short)(r >> 16);
}
__device__ inline float bf2f(unsigned short s) {
  union { unsigned u; float f; } v; v.u = ((unsigned)s) << 16;
  return v.f;
}
__device__ inline float sigmoidf_(float x) { return 1.f / (1.f + __expf(-x)); }
__device__ inline float tanhf_(float x)    { return 2.f / (1.f + __expf(-2.f * x)) - 1.f; }

// ---------------- Projection GEMM: xg[t][b][g] = A[m] @ W^T + b1 + b2 (bf16 out) ----
template<int ABF16, int TROWS>
__global__ __launch_bounds__(256) void proj_kernel(
    const void* __restrict__ Aptr, const float* __restrict__ W,
    const float* __restrict__ bias1, const float* __restrict__ bias2,
    unsigned short* __restrict__ out)
{
  __shared__ short As[128][72];
  __shared__ short Bs[128][72];
  const int tid  = threadIdx.x;
  const int lane = tid & 63;
  const int wv   = tid >> 6;
  const int wm   = wv >> 1, wn = wv & 1;
  const int bid  = blockIdx.x;
  const int nt   = bid & 15;
  const long mbase = (long)(bid >> 4) * 128;
  const int  nbase = nt * 128;

  f32x4 acc[4][4] = {};

  const int r  = tid >> 1;        // 0..127
  const int kh = (tid & 1) * 32;  // k offset within BK

  for (int kt = 0; kt < 8; ++kt) {
    if (ABF16) {
      const unsigned short* src = (const unsigned short*)Aptr + (mbase + r) * 512 + kt * 64 + kh;
      *(short8*)&As[r][kh]      = *(const short8*)(src);
      *(short8*)&As[r][kh + 8]  = *(const short8*)(src + 8);
      *(short8*)&As[r][kh + 16] = *(const short8*)(src + 16);
      *(short8*)&As[r][kh + 24] = *(const short8*)(src + 24);
    } else {
      const float* src = (const float*)Aptr + (mbase + r) * 512 + kt * 64 + kh;
#pragma unroll
      for (int j = 0; j < 4; ++j) {
        float4 v0 = *(const float4*)(src + j * 8);
        float4 v1 = *(const float4*)(src + j * 8 + 4);
        short8 p;
        p[0] = (short)f2bf(v0.x); p[1] = (short)f2bf(v0.y);
        p[2] = (short)f2bf(v0.z); p[3] = (short)f2bf(v0.w);
        p[4] = (short)f2bf(v1.x); p[5] = (short)f2bf(v1.y);
        p[6] = (short)f2bf(v1.z); p[7] = (short)f2bf(v1.w);
        *(short8*)&As[r][kh + j * 8] = p;
      }
    }
    {
      const float* src = W + (size_t)(nbase + r) * 512 + kt * 64 + kh;
#pragma unroll
      for (int j = 0; j < 4; ++j) {
        float4 v0 = *(const float4*)(src + j * 8);
        float4 v1 = *(const float4*)(src + j * 8 + 4);
        short8 p;
        p[0] = (short)f2bf(v0.x); p[1] = (short)f2bf(v0.y);
        p[2] = (short)f2bf(v0.z); p[3] = (short)f2bf(v0.w);
        p[4] = (short)f2bf(v1.x); p[5] = (short)f2bf(v1.y);
        p[6] = (short)f2bf(v1.z); p[7] = (short)f2bf(v1.w);
        *(short8*)&Bs[r][kh + j * 8] = p;
      }
    }
    __syncthreads();
#pragma unroll
    for (int kk = 0; kk < 2; ++kk) {
      const int kc = kk * 32 + ((lane >> 4) & 3) * 8;
      short8 af[4], bfr[4];
#pragma unroll
      for (int i = 0; i < 4; ++i)
        af[i] = *(const short8*)&As[wm * 64 + i * 16 + (lane & 15)][kc];
#pragma unroll
      for (int i = 0; i < 4; ++i)
        bfr[i] = *(const short8*)&Bs[wn * 64 + i * 16 + (lane & 15)][kc];
#pragma unroll
      for (int i = 0; i < 4; ++i)
#pragma unroll
        for (int j = 0; j < 4; ++j)
          acc[i][j] = __builtin_amdgcn_mfma_f32_16x16x32_bf16(af[i], bfr[j], acc[i][j], 0, 0, 0);
    }
    __syncthreads();
  }
#pragma unroll
  for (int j = 0; j < 4; ++j) {
    const int n = nbase + wn * 64 + j * 16 + (lane & 15);
    const float bsum = bias1[n] + bias2[n];
#pragma unroll
    for (int i = 0; i < 4; ++i) {
      f32x4 v = acc[i][j];
#pragma unroll
      for (int e = 0; e < 4; ++e) {
        long m = mbase + wm * 64 + i * 16 + ((lane >> 4) & 3) * 4 + e;
        long orow = TROWS ? ((m & 2047) * 64 + (m >> 11)) : m;
        out[orow * 2048 + n] = f2bf(v[e] + bsum);
      }
    }
  }
}

// ---------------- Persistent scan: 64 WGs = 4 batch-groups x 16 unit-slices --------
// Sync v3: h via sc0+sc1 stores/loads (L3-coherent, no fences). Per-slice flag =
// plain relaxed-agent store of t+1 into its own 128B line (single writer, no RMW).
// Poll: 64 lanes over 16 padded lines, self-throttled by load latency.
template<int LAYER>
__global__ __launch_bounds__(256) void scan_kernel(
    const unsigned short* __restrict__ xg,     // [T][64][2048] bf16
    const float* __restrict__ Whh,             // [2048][512] fp32
    unsigned short* __restrict__ hhist,        // [T+1][64][512] bf16 (this layer)
    float* __restrict__ dout,
    int* __restrict__ flags)                   // [4][16*32] ints (128B per flag)
{
  extern __shared__ char smem[];
  float* gbuf = (float*)(smem + 131072);               // [16][132]
  float* cbuf = (float*)(smem + 131072 + 16 * 132 * 4); // [16][32]

  const int tid  = threadIdx.x;
  const int lane = tid & 63;
  const int wv   = tid >> 6;
  const int s    = blockIdx.x & 15;   // unit slice
  const int grp  = blockIdx.x >> 4;   // batch group
  const int u_base = s * 32;
  const int b_base = grp * 16;
  int* gflags = flags + grp * (16 * 32);

  // ---- load W slice into LDS (bf16, XOR-swizzled rows) ----
  {
    const int r    = tid >> 1;          // 0..127 slice row
    const int kh   = (tid & 1) * 256;   // k half
    const int type = r >> 5, uu = r & 31;
    const float* src = Whh + (size_t)(type * 512 + u_base + uu) * 512 + kh;
    const int rowbyte = r * 1024;
    const int sw = (r & 7) << 4;
#pragma unroll 4
    for (int j = 0; j < 32; ++j) {
      float4 v0 = *(const float4*)(src + j * 8);
      float4 v1 = *(const float4*)(src + j * 8 + 4);
      short8 p;
      p[0] = (short)f2bf(v0.x); p[1] = (short)f2bf(v0.y);
      p[2] = (short)f2bf(v0.z); p[3] = (short)f2bf(v0.w);
      p[4] = (short)f2bf(v1.x); p[5] = (short)f2bf(v1.y);
      p[6] = (short)f2bf(v1.z); p[7] = (short)f2bf(v1.w);
      int byte = rowbyte + (kh + j * 8) * 2;
      *(short8*)(smem + (byte ^ sw)) = p;
    }
  }
  cbuf[tid] = 0.f; cbuf[tid + 256] = 0.f;
  __syncthreads();

  const int bb = tid >> 4;          // cell-phase batch row
  const int u0 = (tid & 15) * 2;    // cell-phase unit pair

  const int rowA = wv * 32 + (lane & 15);
  const int rowB = rowA + 16;
  const int kb   = ((lane >> 4) & 3) * 16;
  const int swA  = (rowA & 7) << 4;
  const int swB  = (rowB & 7) << 4;

  for (int t = 0; t < T_STEPS; ++t) {
    // xg prefetch first: HBM latency hides under the flag poll
    unsigned xgp[4];
    {
      const size_t base = ((size_t)t * 64 + b_base + bb) * 2048 + u_base + u0;
      xgp[0] = *(const unsigned*)(xg + base);
      xgp[1] = *(const unsigned*)(xg + base + 512);
      xgp[2] = *(const unsigned*)(xg + base + 1024);
      xgp[3] = *(const unsigned*)(xg + base + 1536);
    }

    f32x4 a0a = {0.f, 0.f, 0.f, 0.f}, a1a = {0.f, 0.f, 0.f, 0.f};
    f32x4 a0b = {0.f, 0.f, 0.f, 0.f}, a1b = {0.f, 0.f, 0.f, 0.f};

    if (t > 0) {
      // ---- wait for all 16 producers of h[t]: padded flags, relaxed agent loads ----
      {
        int f;
        do {
          f = __hip_atomic_load(&gflags[(lane & 15) * 32], __ATOMIC_RELAXED, __HIP_MEMORY_SCOPE_AGENT);
        } while (!__all(f >= t));
      }
      // ---- h[t] fragment loads, L3-coherent (sc0 sc1); wait only first half ----
      const unsigned short* hrow = hhist + (size_t)t * (64 * 512)
          + (size_t)(b_base + (lane & 15)) * 512 + ((lane >> 4) & 3) * 8;
      short8 hh[16];
      asm volatile(
        "global_load_dwordx4 %0, %16, off sc0 sc1\n\t"
        "global_load_dwordx4 %1, %16, off offset:64 sc0 sc1\n\t"
        "global_load_dwordx4 %2, %16, off offset:128 sc0 sc1\n\t"
        "global_load_dwordx4 %3, %16, off offset:192 sc0 sc1\n\t"
        "global_load_dwordx4 %4, %16, off offset:256 sc0 sc1\n\t"
        "global_load_dwordx4 %5, %16, off offset:320 sc0 sc1\n\t"
        "global_load_dwordx4 %6, %16, off offset:384 sc0 sc1\n\t"
        "global_load_dwordx4 %7, %16, off offset:448 sc0 sc1\n\t"
        "global_load_dwordx4 %8, %16, off offset:512 sc0 sc1\n\t"
        "global_load_dwordx4 %9, %16, off offset:576 sc0 sc1\n\t"
        "global_load_dwordx4 %10, %16, off offset:640 sc0 sc1\n\t"
        "global_load_dwordx4 %11, %16, off offset:704 sc0 sc1\n\t"
        "global_load_dwordx4 %12, %16, off offset:768 sc0 sc1\n\t"
        "global_load_dwordx4 %13, %16, off offset:832 sc0 sc1\n\t"
        "global_load_dwordx4 %14, %16, off offset:896 sc0 sc1\n\t"
        "global_load_dwordx4 %15, %16, off offset:960 sc0 sc1\n\t"
        "s_waitcnt vmcnt(8)"
        : "=&v"(hh[0]), "=&v"(hh[1]), "=&v"(hh[2]), "=&v"(hh[3]),
          "=&v"(hh[4]), "=&v"(hh[5]), "=&v"(hh[6]), "=&v"(hh[7]),
          "=&v"(hh[8]), "=&v"(hh[9]), "=&v"(hh[10]), "=&v"(hh[11]),
          "=&v"(hh[12]), "=&v"(hh[13]), "=&v"(hh[14]), "=&v"(hh[15])
        : "v"(hrow)
        : "memory");
      __builtin_amdgcn_sched_barrier(0);

#pragma unroll
      for (int kt = 0; kt < 8; ++kt) {
        short8 b0 = *(const short8*)(smem + ((rowA * 1024 + kt * 64 + kb) ^ swA));
        short8 b1 = *(const short8*)(smem + ((rowB * 1024 + kt * 64 + kb) ^ swB));
        a0a = __builtin_amdgcn_mfma_f32_16x16x32_bf16(hh[kt], b0, a0a, 0, 0, 0);
        a1a = __builtin_amdgcn_mfma_f32_16x16x32_bf16(hh[kt], b1, a1a, 0, 0, 0);
      }
      asm volatile("s_waitcnt vmcnt(0)" ::: "memory");
      __builtin_amdgcn_sched_barrier(0);
#pragma unroll
      for (int kt = 8; kt < 16; ++kt) {
        short8 b0 = *(const short8*)(smem + ((rowA * 1024 + kt * 64 + kb) ^ swA));
        short8 b1 = *(const short8*)(smem + ((rowB * 1024 + kt * 64 + kb) ^ swB));
        a0b = __builtin_amdgcn_mfma_f32_16x16x32_bf16(hh[kt], b0, a0b, 0, 0, 0);
        a1b = __builtin_amdgcn_mfma_f32_16x16x32_bf16(hh[kt], b1, a1b, 0, 0, 0);
      }
    }

    // write gates to LDS (sum the two half-chains here)
    {
      const int m0 = ((lane >> 4) & 3) * 4;
      const int cA = wv * 32 + (lane & 15);
#pragma unroll
      for (int e = 0; e < 4; ++e) {
        gbuf[(m0 + e) * 132 + cA]      = a0a[e] + a0b[e];
        gbuf[(m0 + e) * 132 + cA + 16] = a1a[e] + a1b[e];
      }
    }
    __syncthreads();

    // cell update: each thread owns (bb, u0) and (bb, u0+1)
    float hv[2], cv[2];
#pragma unroll
    for (int q = 0; q < 2; ++q) {
      const int u = u0 + q;
      float ig = gbuf[bb * 132 + u]        + bf2f((unsigned short)(xgp[0] >> (16 * q)));
      float fg = gbuf[bb * 132 + 32 + u]   + bf2f((unsigned short)(xgp[1] >> (16 * q)));
      float gg = gbuf[bb * 132 + 64 + u]   + bf2f((unsigned short)(xgp[2] >> (16 * q)));
      float og = gbuf[bb * 132 + 96 + u]   + bf2f((unsigned short)(xgp[3] >> (16 * q)));
      float iv = sigmoidf_(ig), fv = sigmoidf_(fg);
      float gv = tanhf_(gg),    ov = sigmoidf_(og);
      float c = fv * cbuf[bb * 32 + u] + iv * gv;
      cbuf[bb * 32 + u] = c;
      float h = ov * tanhf_(c);
      hv[q] = h; cv[q] = c;
    }
    {
      unsigned hp = (unsigned)f2bf(hv[0]) | ((unsigned)f2bf(hv[1]) << 16);
      // L3-coherent h publish (sc0 sc1)
      __hip_atomic_store(
          (unsigned*)(hhist + (size_t)(t + 1) * (64 * 512) + (size_t)(b_base + bb) * 512 + u_base + u0),
          hp, __ATOMIC_RELAXED, __HIP_MEMORY_SCOPE_AGENT);
      if (LAYER == 1) {
        float2 ho; ho.x = hv[0]; ho.y = hv[1];
        *(float2*)(dout + (size_t)(b_base + bb) * ((size_t)T_STEPS * 512) + (size_t)t * 512 + u_base + u0) = ho;
      }
      if (t == T_STEPS - 1) {
        const size_t OUT0 = (size_t)64 * 2048 * 512;
        size_t o  = OUT0 + (size_t)LAYER * 32768 + (size_t)(b_base + bb) * 512 + u_base + u0;
        dout[o]     = hv[0];
        dout[o + 1] = hv[1];
        size_t oc = o + 65536;
        dout[oc]     = cv[0];
        dout[oc + 1] = cv[1];
      }
    }
    __syncthreads();   // drains vmcnt: all h stores acked at coherence point
    if (tid == 0)
      __hip_atomic_store(&gflags[s * 32], t + 1, __ATOMIC_RELAXED, __HIP_MEMORY_SCOPE_AGENT);
  }
}

extern "C" void kernel_launch(void* const* d_in, const int* in_sizes, int n_in,
                              void* d_out, int out_size, void* d_ws, size_t ws_size,
                              hipStream_t stream) {
  const float* x    = (const float*)d_in[0];
  const float* Wih0 = (const float*)d_in[1];
  const float* Whh0 = (const float*)d_in[2];
  const float* bih0 = (const float*)d_in[3];
  const float* bhh0 = (const float*)d_in[4];
  const float* Wih1 = (const float*)d_in[5];
  const float* Whh1 = (const float*)d_in[6];
  const float* bih1 = (const float*)d_in[7];
  const float* bhh1 = (const float*)d_in[8];
  float* out = (float*)d_out;

  const size_t XG_BYTES   = (size_t)T_STEPS * 64 * 2048 * 2;       // 536,870,912
  const size_t H_BYTES    = (size_t)(T_STEPS + 1) * 64 * 512 * 2;  // 134,283,264
  const size_t FLAG_BYTES = (size_t)2 * 4 * 16 * 32 * 4;           // 16,384 (128B/flag)
  if (ws_size < XG_BYTES + 2 * H_BYTES + FLAG_BYTES) return;

  char* ws = (char*)d_ws;
  unsigned short* xg = (unsigned short*)ws;
  unsigned short* h0 = (unsigned short*)(ws + XG_BYTES);
  unsigned short* h1 = (unsigned short*)(ws + XG_BYTES + H_BYTES);
  int* flags         = (int*)(ws + XG_BYTES + 2 * H_BYTES);

  hipMemsetAsync(flags, 0, FLAG_BYTES, stream);

  const int smem_scan = 131072 + 16 * 132 * 4 + 2048;  // 141,568 B
  hipFuncSetAttribute((const void*)scan_kernel<0>, hipFuncAttributeMaxDynamicSharedMemorySize, smem_scan);
  hipFuncSetAttribute((const void*)scan_kernel<1>, hipFuncAttributeMaxDynamicSharedMemorySize, smem_scan);

  proj_kernel<0, 1><<<dim3(16384), dim3(256), 0, stream>>>(x, Wih0, bih0, bhh0, xg);
  scan_kernel<0><<<dim3(64), dim3(256), smem_scan, stream>>>(xg, Whh0, h0, out, flags);
  proj_kernel<1, 0><<<dim3(16384), dim3(256), 0, stream>>>(h0 + 32768, Wih1, bih1, bhh1, xg);
  scan_kernel<1><<<dim3(64), dim3(256), smem_scan, stream>>>(xg, Whh1, h1, out, flags + 4 * 16 * 32);
}